// Round 1
// baseline (214.336 us; speedup 1.0000x reference)
//
#include <hip/hip_runtime.h>

typedef __attribute__((ext_vector_type(8))) short s16x8;
typedef __attribute__((ext_vector_type(4))) float f32x4;

#define CCH 128
#define HWSZ 65536

__device__ __forceinline__ ushort f2bf(float f) {
  uint u = __float_as_uint(f);
  u += 0x7fffu + ((u >> 16) & 1u);
  return (ushort)(u >> 16);
}

// swizzled index into a [row][128] bf16 LDS tile (XOR bits 3-5 of col with row&7)
__device__ __forceinline__ int swz(int row, int col) {
  return (row << 7) | (col ^ ((row & 7) << 3));
}

__global__ __launch_bounds__(256) void prep_weights(const float* __restrict__ w1,
                                                    const float* __restrict__ w2,
                                                    ushort* __restrict__ w1b,
                                                    ushort* __restrict__ w2b) {
  int i = blockIdx.x * 256 + threadIdx.x;  // 0..4095, 4 elems each
  float4 a = ((const float4*)w1)[i];
  ushort4 oa;
  oa.x = f2bf(a.x); oa.y = f2bf(a.y); oa.z = f2bf(a.z); oa.w = f2bf(a.w);
  ((ushort4*)w1b)[i] = oa;
  float4 b = ((const float4*)w2)[i];
  ushort4 ob;
  ob.x = f2bf(b.x); ob.y = f2bf(b.y); ob.z = f2bf(b.z); ob.w = f2bf(b.w);
  ((ushort4*)w2b)[i] = ob;
}

// 1024 blocks: flat 64 (b,g) groups x 16 splits, each block sums 65536 contiguous floats
__global__ __launch_bounds__(256) void stats_partial(const float* __restrict__ x,
                                                     float* __restrict__ partials) {
  const float4* xp = (const float4*)(x + ((size_t)blockIdx.x << 16));
  const int tid = threadIdx.x;
  float s1 = 0.f, s2 = 0.f;
#pragma unroll 8
  for (int i = 0; i < 64; ++i) {
    float4 v = xp[i * 256 + tid];
    s1 += v.x + v.y + v.z + v.w;
    s2 += v.x * v.x + v.y * v.y + v.z * v.z + v.w * v.w;
  }
#pragma unroll
  for (int off = 32; off > 0; off >>= 1) {
    s1 += __shfl_down(s1, off);
    s2 += __shfl_down(s2, off);
  }
  __shared__ float r1[4], r2[4];
  const int wv = tid >> 6;
  if ((tid & 63) == 0) { r1[wv] = s1; r2[wv] = s2; }
  __syncthreads();
  if (tid == 0) {
    partials[blockIdx.x * 2]     = r1[0] + r1[1] + r1[2] + r1[3];
    partials[blockIdx.x * 2 + 1] = r2[0] + r2[1] + r2[2] + r2[3];
  }
}

// 64 threads: one per (b,g). Fold mean/rstd with gn_w/gn_b into per-(b,c) scale/shift.
__global__ void stats_finalize(const float* __restrict__ partials,
                               const float* __restrict__ gn_w,
                               const float* __restrict__ gn_b,
                               float* __restrict__ scale, float* __restrict__ shift) {
  const int t = threadIdx.x;
  float s1 = 0.f, s2 = 0.f;
#pragma unroll
  for (int i = 0; i < 16; ++i) {
    s1 += partials[(t * 16 + i) * 2];
    s2 += partials[(t * 16 + i) * 2 + 1];
  }
  const float invN = 1.0f / 1048576.0f;
  const float mean = s1 * invN;
  const float var = s2 * invN - mean * mean;
  const float rstd = rsqrtf(var + 1e-5f);
  const int b = t >> 3, g = t & 7;
  for (int i = 0; i < 16; ++i) {
    const int c = g * 16 + i;
    const float sc = rstd * gn_w[c];
    scale[b * CCH + c] = sc;
    shift[b * CCH + c] = gn_b[c] - mean * sc;
  }
}

// 4096 blocks (8 batches x 512 tiles of 128 pixels), 256 threads = 4 waves.
__global__ __launch_bounds__(256) void fused_main(
    const float* __restrict__ x, const ushort* __restrict__ w1b,
    const ushort* __restrict__ w2b, const float* __restrict__ scale,
    const float* __restrict__ shift, const float* __restrict__ b1,
    const float* __restrict__ b2, float* __restrict__ out) {
  __shared__ ushort sB[128 * 128];  // [pixel][chan] bf16, swizzled
  const int tid = threadIdx.x;
  const int b = blockIdx.x >> 9;
  const int p0 = (blockIdx.x & 511) << 7;
  const int lane = tid & 63;
  const int wv = tid >> 6;
  const int fl = lane & 15;
  const int fh = lane >> 4;

  // ---- stage: xn = x*scale + shift -> bf16 tile in LDS ----
  {
    const int p = tid & 127;               // pixel owned by this thread
    const int ch0 = (tid >> 7) << 6;       // channel half: 0 or 64 (wave-uniform)
    const float* xb = x + (((size_t)b * CCH) << 16) + p0 + p;
    const float* scb = scale + b * CCH;
    const float* shb = shift + b * CCH;
#pragma unroll
    for (int cc = 0; cc < 64; cc += 16) {
      float v[16];
#pragma unroll
      for (int i = 0; i < 16; ++i)
        v[i] = xb[((size_t)(ch0 + cc + i)) << 16];
#pragma unroll
      for (int q = 0; q < 4; ++q) {
        const int c = ch0 + cc + q * 4;
        ushort4 pk;
        pk.x = f2bf(v[q * 4 + 0] * scb[c + 0] + shb[c + 0]);
        pk.y = f2bf(v[q * 4 + 1] * scb[c + 1] + shb[c + 1]);
        pk.z = f2bf(v[q * 4 + 2] * scb[c + 2] + shb[c + 2]);
        pk.w = f2bf(v[q * 4 + 3] * scb[c + 3] + shb[c + 3]);
        *(ushort4*)&sB[swz(p, c)] = pk;
      }
    }
  }
  __syncthreads();

  // ---- GEMM1: h = relu(w1 . xn + b1); A-frags from global bf16 weights ----
  f32x4 acc[2][8];
#pragma unroll
  for (int f = 0; f < 2; ++f)
#pragma unroll
    for (int j = 0; j < 8; ++j)
      acc[f][j] = (f32x4){0.f, 0.f, 0.f, 0.f};

#pragma unroll
  for (int k0 = 0; k0 < 128; k0 += 32) {
    const int kb = k0 + fh * 8;
    const s16x8 a0 = *(const s16x8*)(w1b + (wv * 32 + fl) * CCH + kb);
    const s16x8 a1 = *(const s16x8*)(w1b + (wv * 32 + 16 + fl) * CCH + kb);
#pragma unroll
    for (int j = 0; j < 8; ++j) {
      const s16x8 bf = *(const s16x8*)&sB[swz(j * 16 + fl, kb)];
      acc[0][j] = __builtin_amdgcn_mfma_f32_16x16x32_bf16(a0, bf, acc[0][j], 0, 0, 0);
      acc[1][j] = __builtin_amdgcn_mfma_f32_16x16x32_bf16(a1, bf, acc[1][j], 0, 0, 0);
    }
  }
  __syncthreads();  // all sB reads complete before overwrite

  // ---- bias + relu, write H back into sB as [pixel][out_chan] ----
#pragma unroll
  for (int f = 0; f < 2; ++f) {
    const int ob = wv * 32 + f * 16 + fh * 4;
    float bb[4];
#pragma unroll
    for (int r = 0; r < 4; ++r) bb[r] = b1[ob + r];
#pragma unroll
    for (int j = 0; j < 8; ++j) {
      const int pcol = j * 16 + fl;
      ushort4 pk;
      pk.x = f2bf(fmaxf(acc[f][j][0] + bb[0], 0.f));
      pk.y = f2bf(fmaxf(acc[f][j][1] + bb[1], 0.f));
      pk.z = f2bf(fmaxf(acc[f][j][2] + bb[2], 0.f));
      pk.w = f2bf(fmaxf(acc[f][j][3] + bb[3], 0.f));
      *(ushort4*)&sB[swz(pcol, ob)] = pk;
    }
  }
  __syncthreads();

  // ---- GEMM2: ffn = w2 . h + b2 ----
  f32x4 acc2[2][8];
#pragma unroll
  for (int f = 0; f < 2; ++f)
#pragma unroll
    for (int j = 0; j < 8; ++j)
      acc2[f][j] = (f32x4){0.f, 0.f, 0.f, 0.f};

#pragma unroll
  for (int k0 = 0; k0 < 128; k0 += 32) {
    const int kb = k0 + fh * 8;
    const s16x8 a0 = *(const s16x8*)(w2b + (wv * 32 + fl) * CCH + kb);
    const s16x8 a1 = *(const s16x8*)(w2b + (wv * 32 + 16 + fl) * CCH + kb);
#pragma unroll
    for (int j = 0; j < 8; ++j) {
      const s16x8 bf = *(const s16x8*)&sB[swz(j * 16 + fl, kb)];
      acc2[0][j] = __builtin_amdgcn_mfma_f32_16x16x32_bf16(a0, bf, acc2[0][j], 0, 0, 0);
      acc2[1][j] = __builtin_amdgcn_mfma_f32_16x16x32_bf16(a1, bf, acc2[1][j], 0, 0, 0);
    }
  }

  // ---- epilogue: out = x + ffn + b2 ----
#pragma unroll
  for (int f = 0; f < 2; ++f) {
    const int ob = wv * 32 + f * 16 + fh * 4;
    float bb[4];
#pragma unroll
    for (int r = 0; r < 4; ++r) bb[r] = b2[ob + r];
#pragma unroll
    for (int j = 0; j < 8; ++j) {
      const int pcol = p0 + j * 16 + fl;
      const size_t base = (((size_t)(b * CCH + ob)) << 16) + pcol;
#pragma unroll
      for (int r = 0; r < 4; ++r) {
        const size_t idx = base + ((size_t)r << 16);
        out[idx] = x[idx] + acc2[f][j][r] + bb[r];
      }
    }
  }
}

extern "C" void kernel_launch(void* const* d_in, const int* in_sizes, int n_in,
                              void* d_out, int out_size, void* d_ws, size_t ws_size,
                              hipStream_t stream) {
  const float* x    = (const float*)d_in[0];
  const float* gn_w = (const float*)d_in[1];
  const float* gn_b = (const float*)d_in[2];
  const float* w1   = (const float*)d_in[3];
  const float* b1   = (const float*)d_in[4];
  const float* w2   = (const float*)d_in[5];
  const float* b2   = (const float*)d_in[6];
  float* out = (float*)d_out;

  char* ws = (char*)d_ws;
  float* partials = (float*)ws;                    // 2048 floats (8 KiB)
  float* scale    = (float*)(ws + 8192);           // 1024 floats
  float* shift    = (float*)(ws + 12288);          // 1024 floats
  ushort* w1b     = (ushort*)(ws + 16384);         // 32 KiB
  ushort* w2b     = (ushort*)(ws + 49152);         // 32 KiB

  hipLaunchKernelGGL(prep_weights, dim3(16), dim3(256), 0, stream, w1, w2, w1b, w2b);
  hipLaunchKernelGGL(stats_partial, dim3(1024), dim3(256), 0, stream, x, partials);
  hipLaunchKernelGGL(stats_finalize, dim3(1), dim3(64), 0, stream, partials, gn_w, gn_b, scale, shift);
  hipLaunchKernelGGL(fused_main, dim3(4096), dim3(256), 0, stream, x, w1b, w2b, scale, shift, b1, b2, out);
}